// Round 1
// baseline (284.781 us; speedup 1.0000x reference)
//
#include <hip/hip_runtime.h>

// Compress70: T_lv2 = fold(gather(unfold(lv2,3,1,1)))/9 ; T_lv1 = fold(gather(unfold(lv1,6,2,2)))/9
// Rewritten as pure per-output-pixel gathers (no scatter/atomics).
//
// Shapes: lv1 [2,64,256,256] f32, lv2 [2,128,128,128] f32, h_index [2,16384] int
// out = concat(T_lv2 [2,128,128,128], T_lv1 [2,64,256,256]) flat f32.

#define HH 128
#define WW 128

__global__ __launch_bounds__(256) void t_lv2_kernel(
    const float* __restrict__ lv2, const int* __restrict__ hidx,
    float* __restrict__ out)
{
    int t = blockIdx.x * 256 + threadIdx.x;       // < 2*128*128*128
    int x  = t & (WW - 1);
    int y  = (t >> 7) & (HH - 1);
    int bc = t >> 14;                              // b*128 + c
    int b  = t >> 21;
    const int*   hb  = hidx + (b << 14);
    const float* src = lv2 + ((long)bc << 14);
    float acc = 0.f;
#pragma unroll
    for (int da = -1; da <= 1; ++da) {
        int a = y + da;
        if ((unsigned)a >= (unsigned)HH) continue;
#pragma unroll
        for (int de = -1; de <= 1; ++de) {
            int e = x + de;
            if ((unsigned)e >= (unsigned)WW) continue;
            int p  = hb[(a << 7) + e];
            int sr = (p >> 7) - da;                // p_y + (y - a)
            int sc = (p & (WW - 1)) - de;          // p_x + (x - e)
            if ((unsigned)sr < (unsigned)HH && (unsigned)sc < (unsigned)WW)
                acc += src[(sr << 7) + sc];
        }
    }
    out[t] = acc * (1.f / 9.f);
}

__global__ __launch_bounds__(256) void t_lv1_kernel(
    const float* __restrict__ lv1, const int* __restrict__ hidx,
    float* __restrict__ out)
{
    int t = blockIdx.x * 256 + threadIdx.x;       // < 2*64*256*256
    int X  = t & 255;
    int Y  = (t >> 8) & 255;
    int bc = t >> 16;                              // b*64 + c
    int b  = t >> 22;
    const int*   hb  = hidx + (b << 14);
    const float* src = lv1 + ((long)bc << 16);
    int jyh = (Y + 2) >> 1;                        // max patch row covering Y
    int jxh = (X + 2) >> 1;
    float acc = 0.f;
#pragma unroll
    for (int ka = 0; ka < 3; ++ka) {
        int jy = jyh - ka;
        if ((unsigned)jy >= (unsigned)HH) continue;
        int dy = Y - 2 * jy;                       // in {-2,0,2} or {-1,1,3}
#pragma unroll
        for (int kb = 0; kb < 3; ++kb) {
            int jx = jxh - kb;
            if ((unsigned)jx >= (unsigned)WW) continue;
            int dx = X - 2 * jx;
            int p  = hb[(jy << 7) + jx];
            int sr = 2 * (p >> 7) + dy;
            int sc = 2 * (p & (WW - 1)) + dx;
            if ((unsigned)sr < 256u && (unsigned)sc < 256u)
                acc += src[(sr << 8) + sc];
        }
    }
    out[t] = acc * (1.f / 9.f);
}

extern "C" void kernel_launch(void* const* d_in, const int* in_sizes, int n_in,
                              void* d_out, int out_size, void* d_ws, size_t ws_size,
                              hipStream_t stream)
{
    const float* lv1  = (const float*)d_in[0];
    const float* lv2  = (const float*)d_in[1];
    const int*   hidx = (const int*)d_in[2];
    float* out = (float*)d_out;

    const int N2 = 2 * 128 * 128 * 128;   // 4194304  (T_lv2 elements)
    const int N1 = 2 * 64 * 256 * 256;    // 8388608  (T_lv1 elements)

    t_lv2_kernel<<<N2 / 256, 256, 0, stream>>>(lv2, hidx, out);
    t_lv1_kernel<<<N1 / 256, 256, 0, stream>>>(lv1, hidx, out + N2);
}